// Round 10
// baseline (259.352 us; speedup 1.0000x reference)
//
#include <hip/hip_runtime.h>
#include <hip/hip_bf16.h>

#define NN 1024   // nodes = 32*32
#define EE 1984   // grid edges

// ---------------- edge index -> endpoints (matches grid_edges) ----------------
__device__ __forceinline__ void edge_uv(int e, int* u, int* v) {
    if (e < 992) {             // horizontal: idx[:, :-1] -> idx[:, 1:]
        int r = e / 31, c = e - r * 31;
        *u = r * 32 + c; *v = *u + 1;
    } else {                   // vertical: idx[:-1, :] -> idx[1:, :]
        *u = e - 992; *v = *u + 32;
    }
}

// ======================= conv 1x1 tile (1024 threads) ========================
__device__ void conv1x1_tile(const float* __restrict__ in, const float* __restrict__ in2,
                             const float* __restrict__ w,
                             float* __restrict__ out, int CIN, int Cout,
                             int b, int co0, int n0, float* red) {
    int tid = threadIdx.x;
    int px = tid & 63, kc = tid >> 6;
    int kcu = __builtin_amdgcn_readfirstlane(kc);   // wave-uniform -> s_loads for w
    int KCH = CIN >> 4;
    size_t ibase = (size_t)b * CIN * NN + n0 + px;
    const float* wr = w + (size_t)co0 * CIN;
    float acc[8] = {0.f,0.f,0.f,0.f,0.f,0.f,0.f,0.f};
    for (int ci = kcu * KCH; ci < kcu * KCH + KCH; ++ci) {
        float xv = in[ibase + (size_t)ci * NN];
        if (in2) xv += in2[ibase + (size_t)ci * NN];
#pragma unroll
        for (int j = 0; j < 8; ++j)
            acc[j] += wr[j * CIN + ci] * xv;
    }
#pragma unroll
    for (int j = 0; j < 8; ++j) red[j * 1024 + tid] = acc[j];
    __syncthreads();
    for (int s = 8; s >= 1; s >>= 1) {
        if (kc < s) {
#pragma unroll
            for (int j = 0; j < 8; ++j)
                red[j * 1024 + kc * 64 + px] += red[j * 1024 + (kc + s) * 64 + px];
        }
        __syncthreads();
    }
    if (kc == 0) {
        size_t ob = ((size_t)b * Cout + co0) * NN + n0 + px;
#pragma unroll
        for (int j = 0; j < 8; ++j) out[ob + (size_t)j * NN] = red[j * 1024 + px];
    }
}

// ======================= edge-dist tile (1024 threads) =======================
__device__ void dist_tile(const float* __restrict__ fm, float* __restrict__ dist,
                          int b, int eb, float* red) {
    int tid = threadIdx.x;
    int le = tid & 63, kc = tid >> 6;
    int kcu = __builtin_amdgcn_readfirstlane(kc);
    int e = eb * 64 + le;                  // 31*64 == 1984 exact
    int u, v; edge_uv(e, &u, &v);
    const float* fp = fm + (size_t)b * 1024 * NN;
    float s = 0.f;
    for (int c = kcu * 64; c < kcu * 64 + 64; ++c) {
        float d = fp[(size_t)c * NN + u] - fp[(size_t)c * NN + v];
        s += d * d;
    }
    red[tid] = s;
    __syncthreads();
    for (int ss = 8; ss >= 1; ss >>= 1) {
        if (kc < ss) red[kc * 64 + le] += red[(kc + ss) * 64 + le];
        __syncthreads();
    }
    if (kc == 0) dist[b * EE + e] = red[le];
}

// ================== conv 3x3 body (256 threads, 2-half staging) ==============
__device__ void conv3x3_body(const float* __restrict__ in, const float* __restrict__ w,
                             const float* __restrict__ gg, const float* __restrict__ bb,
                             const float* __restrict__ mm, const float* __restrict__ vv,
                             const float* __restrict__ res, float* __restrict__ out,
                             int mode, int b, int co, int r0, float* pl) {
    int tid = threadIdx.x;
    const float* ip = in + (size_t)b * 64 * NN;
    const float* wp = w + (size_t)co * 64 * 9;
    int r = tid >> 5, c = tid & 31;
    float acc = 0.f;
    for (int h = 0; h < 2; ++h) {
        __syncthreads();
        for (int i4 = tid; i4 < 32 * 80; i4 += 256) {    // float4 staging
            int ci = i4 / 80, o = i4 - ci * 80;
            int row = r0 - 1 + (o >> 3), c4 = (o & 7) << 2;
            float4 val = make_float4(0.f, 0.f, 0.f, 0.f);
            if (row >= 0 && row < 32)
                val = *(const float4*)&ip[(size_t)(h * 32 + ci) * NN + row * 32 + c4];
            *(float4*)&pl[ci * 320 + (o >> 3) * 32 + c4] = val;
        }
        __syncthreads();
        for (int ci = 0; ci < 32; ++ci) {
            float wv[9];
#pragma unroll
            for (int q = 0; q < 9; ++q) wv[q] = wp[(h * 32 + ci) * 9 + q];  // uniform
            float s = 0.f;
#pragma unroll
            for (int dy = 0; dy < 3; ++dy) {
                const float* row = &pl[ci * 320 + (r + dy) * 32];
#pragma unroll
                for (int dx = -1; dx <= 1; ++dx) {
                    int cc = c + dx;
                    float xv = (cc >= 0 && cc < 32) ? row[cc] : 0.f;
                    s += wv[dy * 3 + (dx + 1)] * xv;
                }
            }
            acc += s;
        }
    }
    float val;
    size_t op = ((size_t)b * 64 + co) * NN + r0 * 32 + tid;
    if (mode == 0) {
        float sc = gg[co] * rsqrtf(vv[co] + 1e-5f);
        val = acc * sc + (bb[co] - mm[co] * sc);
    } else {
        val = acc + res[op];
    }
    out[op] = fmaxf(val, 0.f);
}

// ===================== MST state (LDS, ~57 KB) ===============================
struct MstS {
    unsigned long long minkey[NN];   // later reused as off[] ints
    unsigned long long ekey[EE];     // later reused as depth ping-pong buffers
    int parent[NN], pnw[NN], pn[NN], dep[NN], scr[NN], elist[NN];
    int mstm[EE];
    int cnt, cnt2;
};

// ========== MST body: 256 threads (4 nodes/thread), reference-faithful =======
// 14 re-singleton Boruvka rounds (early exit at N-1 mask edges: every added
// edge is a min cut edge => mask subset of final => complete == final).
// Node-gather min (1 atomic/node). Adaptive in-place 2-jump flatten to fixed
// point (== reference's 12 doublings). BFS with 16 unsynced volatile scans per
// barrier epoch (write-once race benign in a tree). Depth: 12-step pointer
// doubling with JAX -1 -> N-1 wrap; adaptive exit exact when BFS reached all
// nodes (then depth stabilizes once all pointers hit root), full 12 otherwise.
// Counting sort -> depth-ordered node list + level offsets.
__device__ void mst_body_256(const float* __restrict__ dist, int b, MstS* S,
                             int* __restrict__ pn_g, int* __restrict__ maxd_g,
                             int* __restrict__ ord_g, int* __restrict__ off_g) {
    int tid = threadIdx.x;            // 0..255
    const float* wb = dist + b * EE;
#pragma unroll
    for (int k = 0; k < 4; ++k) {
        int v = tid + k * 256;
        S->parent[v] = v;
        S->minkey[v] = ~0ULL;
    }
    for (int e = tid; e < EE; e += 256) {
        S->mstm[e] = 0;
        S->ekey[e] = ((unsigned long long)__float_as_uint(wb[e]) << 32) | (unsigned)e;
    }
    if (tid == 0) { S->cnt = 0; S->cnt2 = 0; }
    __syncthreads();

    for (int round = 0; round < 14; ++round) {
        // node-gather min over incident cross edges; one atomic per node
#pragma unroll
        for (int k = 0; k < 4; ++k) {
            int v = tid + k * 256;
            int r = v >> 5, c = v & 31;
            int pv = S->parent[v];
            unsigned long long mk = ~0ULL;
            if (c < 31 && S->parent[v + 1] != pv) {
                unsigned long long kk = S->ekey[r * 31 + c]; if (kk < mk) mk = kk;
            }
            if (c > 0 && S->parent[v - 1] != pv) {
                unsigned long long kk = S->ekey[r * 31 + c - 1]; if (kk < mk) mk = kk;
            }
            if (r < 31 && S->parent[v + 32] != pv) {
                unsigned long long kk = S->ekey[992 + r * 32 + c]; if (kk < mk) mk = kk;
            }
            if (r > 0 && S->parent[v - 32] != pv) {
                unsigned long long kk = S->ekey[992 + (r - 1) * 32 + c]; if (kk < mk) mk = kk;
            }
            if (mk != ~0ULL) atomicMin(&S->minkey[pv], mk);
        }
        __syncthreads();
#pragma unroll
        for (int k = 0; k < 4; ++k) {
            int v = tid + k * 256;
            int np;
            unsigned long long sel = S->minkey[v];
            S->minkey[v] = ~0ULL;          // fused reset (only v's owner reads it)
            if (sel != ~0ULL) {
                int e = (int)(sel & 0xffffffffULL);
                if (atomicExch(&S->mstm[e], 1) == 0) atomicAdd(&S->cnt, 1);
                int eu, ev; edge_uv(e, &eu, &ev);
                int cu = S->parent[eu], cv = S->parent[ev];
                np = (cu == v) ? cv : cu;
            } else np = v;                 // reference: re-singleton when !valid
            S->pnw[v] = np;
        }
        __syncthreads();
#pragma unroll
        for (int k = 0; k < 4; ++k) {      // break mutual 2-cycles
            int v = tid + k * 256;
            int q = S->pnw[v];
            int pq = S->pnw[q];
            S->parent[v] = (pq == v && v < q) ? v : q;
        }
        __syncthreads();                   // parent fully written before flatten
        for (;;) {                         // adaptive in-place 2-jump flatten
            int ch = 0;
#pragma unroll
            for (int k = 0; k < 4; ++k) {
                int v = tid + k * 256;
                int p = S->parent[v];
                p = S->parent[p];
                p = S->parent[p];
                S->parent[v] = p;
                if (S->parent[p] != p) ch = 1;   // p not a root yet
            }
            if (!__syncthreads_or(ch)) break;
        }
        if (S->cnt == NN - 1) break;       // mask complete => final
    }

    // ---- compact MST edge list ----
    for (int e = tid; e < EE; e += 256)
        if (S->mstm[e]) { int s = atomicAdd(&S->cnt2, 1); S->elist[s] = e; }
    __syncthreads();
    int ecnt = S->cnt2;

    // ---- BFS from node 0: 16 unsynced volatile scans per barrier epoch ----
#pragma unroll
    for (int k = 0; k < 4; ++k) { int v = tid + k * 256; S->pn[v] = (v == 0) ? 0 : -1; }
    __syncthreads();
    volatile int* vpn = S->pn;
    int eu_[4], ev_[4];
    bool have[4];
#pragma unroll
    for (int k = 0; k < 4; ++k) {
        int idx = tid + k * 256;
        have[k] = idx < ecnt;
        eu_[k] = 0; ev_[k] = 0;
        if (have[k]) edge_uv(S->elist[idx], &eu_[k], &ev_[k]);
    }
    for (;;) {
        int ch = 0;
        for (int s = 0; s < 16; ++s) {
#pragma unroll
            for (int k = 0; k < 4; ++k) {
                if (have[k]) {
                    int pu = vpn[eu_[k]], pv = vpn[ev_[k]];
                    if (pu >= 0 && pv < 0)      { vpn[ev_[k]] = eu_[k]; ch = 1; }
                    else if (pv >= 0 && pu < 0) { vpn[eu_[k]] = ev_[k]; ch = 1; }
                }
            }
        }
        if (!__syncthreads_or(ch)) break;
    }
    int incomplete = __syncthreads_or((S->pn[tid] < 0) | (S->pn[tid + 256] < 0) |
                                      (S->pn[tid + 512] < 0) | (S->pn[tid + 768] < 0));

    // ---- depth: pointer doubling, -1 wraps to N-1; ping-pong in ekey space ----
#pragma unroll
    for (int k = 0; k < 4; ++k) {
        int v = tid + k * 256;
        S->dep[v] = (v != 0) ? 1 : 0;
        S->pnw[v] = S->pn[v];
    }
    __syncthreads();
    int* dA = S->dep;                  int* dB = (int*)S->ekey;
    int* pA = S->pnw;                  int* pB = ((int*)S->ekey) + NN;
    for (int it = 0; it < 12; ++it) {
        int allz = 1;
#pragma unroll
        for (int k = 0; k < 4; ++k) {
            int v = tid + k * 256;
            int p = pA[v];
            int j = (p < 0) ? (NN + p) : p;
            dB[v] = dA[v] + dA[j];
            int nx = pA[j];
            pB[v] = nx;
            if (nx != 0) allz = 0;
        }
        int fin = (!incomplete) && (!__syncthreads_or(!allz));
        int* t = dA; dA = dB; dB = t;
        t = pA; pA = pB; pB = t;
        if (fin) break;                // all pointers at root: depth stable
    }
    if (tid == 0) S->cnt = 0;
    __syncthreads();
    int dloc[4], lm = 0;
#pragma unroll
    for (int k = 0; k < 4; ++k) {
        dloc[k] = dA[tid + k * 256];
        if (dloc[k] >= 1 && dloc[k] <= NN - 1 && dloc[k] > lm) lm = dloc[k];
    }
    atomicMax(&S->cnt, lm);
    // counting sort by depth (bucket 0 = root + out-of-range)
#pragma unroll
    for (int k = 0; k < 4; ++k) S->scr[tid + k * 256] = 0;
    __syncthreads();
    int maxd = S->cnt;
    int bkt[4];
#pragma unroll
    for (int k = 0; k < 4; ++k) {
        int v = tid + k * 256;
        bkt[k] = (v != 0 && dloc[k] >= 1 && dloc[k] <= NN - 1) ? dloc[k] : 0;
        atomicAdd(&S->scr[bkt[k]], 1);
    }
    __syncthreads();
    // prefix over 1024 buckets: thread t owns buckets 4t..4t+3
    int base = tid * 4;
    int c0 = S->scr[base], c1 = S->scr[base + 1], c2 = S->scr[base + 2], c3 = S->scr[base + 3];
    int run = c0 + c1 + c2 + c3;
    int lane = tid & 63, wid = tid >> 6;
    int x = run;
    for (int d2 = 1; d2 < 64; d2 <<= 1) {
        int y = __shfl_up(x, d2, 64);
        if (lane >= d2) x += y;
    }
    if (lane == 63) S->pnw[wid] = x;       // wave totals
    __syncthreads();
    if (tid < 4) {
        int off = 0;
        for (int i = 0; i < tid; ++i) off += S->pnw[i];
        S->parent[tid] = off;
    }
    __syncthreads();
    int excl = x - run + S->parent[wid];
    int* mi = (int*)S->minkey;             // minkey free now: level offsets
    mi[base]     = excl;
    mi[base + 1] = excl + c0;
    mi[base + 2] = excl + c0 + c1;
    mi[base + 3] = excl + c0 + c1 + c2;
    S->scr[base]     = mi[base];           // running counters
    S->scr[base + 1] = mi[base + 1];
    S->scr[base + 2] = mi[base + 2];
    S->scr[base + 3] = mi[base + 3];
    __syncthreads();
#pragma unroll
    for (int k = 0; k < 4; ++k) {
        int v = tid + k * 256;
        int pos = atomicAdd(&S->scr[bkt[k]], 1);
        S->elist[pos] = v;                 // elist reused as ord
    }
    __syncthreads();

    // ---- outputs ----
#pragma unroll
    for (int k = 0; k < 4; ++k) {
        int v = tid + k * 256;
        pn_g[b * NN + v]    = S->pn[v];
        ord_g[b * NN + v]   = S->elist[v];
        off_g[b * 1025 + v] = mi[v];
    }
    if (tid == 0) { off_g[b * 1025 + 1024] = NN; maxd_g[b] = maxd; }
}

// =============== tree filter body: ONE WAVE, level-list driven ===============
struct TfSmem { float agg[NN * 3]; float wv[NN]; int jj[NN]; int ords[NN]; int offs[1025]; };
__device__ void treefilter_wave(const float* __restrict__ feat, const float* __restrict__ emb,
                                const int* __restrict__ pn_g, const int* __restrict__ ord_g,
                                const int* __restrict__ off_g, const int* __restrict__ maxd_g,
                                float* __restrict__ tfout, int b, int g, int sub, TfSmem* S) {
    int lane = threadIdx.x;
    const float* eb = emb + ((size_t)b * 32 + g * 8) * NN;
    int c0 = g * 16 + sub * 2;
    const float* fb = feat + ((size_t)b * 64 + c0) * NN;
    for (int k = 0; k < 16; ++k) {
        int v = lane + k * 64;
        int p = pn_g[b * NN + v];
        int j = (p < 0) ? (NN + p) : p;        // JAX negative indexing
        S->jj[v] = j;
        float s = 0.f;
#pragma unroll
        for (int q = 0; q < 8; ++q) {
            float d = eb[(size_t)q * NN + v] - eb[(size_t)q * NN + j];
            s += d * d;
        }
        S->wv[v] = expf(-s);
        S->agg[v * 3 + 0] = fb[v];
        S->agg[v * 3 + 1] = fb[NN + v];
        S->agg[v * 3 + 2] = 1.f;
        S->ords[v] = ord_g[b * NN + v];
        S->offs[v] = off_g[b * 1025 + v];
    }
    if (lane == 0) S->offs[1024] = NN;
    int maxdep = maxd_g[b];
    for (int lev = maxdep; lev >= 1; --lev) {             // up sweep
        int s0 = S->offs[lev], s1 = S->offs[lev + 1];
        for (int i = s0 + lane; i < s1; i += 64) {
            int v = S->ords[i]; int j = S->jj[v]; float w = S->wv[v];
            atomicAdd(&S->agg[j * 3 + 0], w * S->agg[v * 3 + 0]);
            atomicAdd(&S->agg[j * 3 + 1], w * S->agg[v * 3 + 1]);
            atomicAdd(&S->agg[j * 3 + 2], w * S->agg[v * 3 + 2]);
        }
    }
    for (int lev = 1; lev <= maxdep; ++lev) {             // down sweep (in place)
        int s0 = S->offs[lev], s1 = S->offs[lev + 1];
        for (int i = s0 + lane; i < s1; i += 64) {
            int v = S->ords[i]; int j = S->jj[v]; float w = S->wv[v];
#pragma unroll
            for (int c = 0; c < 3; ++c) {
                float a = S->agg[v * 3 + c];
                S->agg[v * 3 + c] = a + w * (S->agg[j * 3 + c] - w * a);
            }
        }
    }
    float* ob = tfout + ((size_t)b * 64 + c0) * NN;
    for (int k = 0; k < 16; ++k) {
        int v = lane + k * 64;
        float inv = 1.f / S->agg[v * 3 + 2];
        ob[v]      = S->agg[v * 3 + 0] * inv;
        ob[NN + v] = S->agg[v * 3 + 1] * inv;
    }
}

// ======== K0: dist (62) + big conv1x1 (256) + embed conv (128) @1024 =========
__global__ __launch_bounds__(1024) void k0_fused(
    const float* __restrict__ fm, const float* __restrict__ last_fm,
    const float* __restrict__ lat_w1, const float* __restrict__ emb_w,
    float* __restrict__ lat_x1, float* __restrict__ embed, float* __restrict__ dist) {
    __shared__ __align__(16) float red[8192];
    int bx = blockIdx.x;
    if (bx < 62) {
        dist_tile(fm, dist, bx / 31, bx % 31, red);
    } else if (bx < 318) {
        int i = bx - 62, b = i >> 7, r = i & 127;
        conv1x1_tile(fm, nullptr, lat_w1, lat_x1, 1024, 64,
                     b, (r >> 4) * 8, (r & 15) * 64, red);
    } else {
        int i = bx - 318, b = i >> 6, r = i & 63;
        conv1x1_tile(last_fm, nullptr, emb_w, embed, 64, 32,
                     b, (r >> 4) * 8, (r & 15) * 64, red);
    }
}

// ============== K1: MST (blocks 0,1) || conv3x3a (512) @256 ==================
union K1S { float pl[32 * 320]; MstS m; };
__global__ __launch_bounds__(256) void k1_fused(
    const float* __restrict__ dist, int* __restrict__ pn_g,
    int* __restrict__ maxd_g, int* __restrict__ ord_g, int* __restrict__ off_g,
    const float* __restrict__ lat_x1, const float* __restrict__ lat_w3a,
    const float* __restrict__ lat_g, const float* __restrict__ lat_b,
    const float* __restrict__ lat_m, const float* __restrict__ lat_v,
    float* __restrict__ lat_t1) {
    __shared__ __align__(16) K1S s;
    int bx = blockIdx.x;
    if (bx < 2) {
        mst_body_256(dist, bx, &s.m, pn_g, maxd_g, ord_g, off_g);
    } else {
        int i = bx - 2, b = i >> 8, co = (i >> 2) & 63, r0 = (i & 3) * 8;
        conv3x3_body(lat_x1, lat_w3a, lat_g, lat_b, lat_m, lat_v,
                     nullptr, lat_t1, 0, b, co, r0, s.pl);
    }
}

// ============ K2: treefilter (blocks 0..63) || conv3x3b (512) @256 ===========
union K2S { float pl[32 * 320]; TfSmem t; };
__global__ __launch_bounds__(256) void k2_fused(
    const float* __restrict__ last_fm, const float* __restrict__ embed,
    const int* __restrict__ pn_g, const int* __restrict__ ord_g,
    const int* __restrict__ off_g, const int* __restrict__ maxd_g,
    float* __restrict__ tfout,
    const float* __restrict__ lat_t1, const float* __restrict__ lat_w3b,
    const float* __restrict__ lat_x1, float* __restrict__ latent) {
    __shared__ __align__(16) K2S s;
    int bx = blockIdx.x;
    if (bx < 64) {
        if (threadIdx.x >= 64) return;     // single wave, no barriers inside
        treefilter_wave(last_fm, embed, pn_g, ord_g, off_g, maxd_g, tfout,
                        bx >> 5, (bx >> 3) & 3, bx & 7, &s.t);
    } else {
        int i = bx - 64, b = i >> 8, co = (i >> 2) & 63, r0 = (i & 3) * 8;
        conv3x3_body(lat_t1, lat_w3b, nullptr, nullptr, nullptr, nullptr,
                     lat_x1, latent, 1, b, co, r0, s.pl);
    }
}

// ===================== standalone tail kernels ===============================
__global__ __launch_bounds__(256) void conv3x3_kernel(
    const float* __restrict__ in, const float* __restrict__ w,
    const float* __restrict__ gg, const float* __restrict__ bb,
    const float* __restrict__ mm, const float* __restrict__ vv,
    const float* __restrict__ res, float* __restrict__ out, int mode) {
    __shared__ __align__(16) float pl[32 * 320];
    conv3x3_body(in, w, gg, bb, mm, vv, res, out, mode,
                 blockIdx.z, blockIdx.y, blockIdx.x * 8, pl);
}

__global__ __launch_bounds__(1024) void conv1x1_add_kernel(
    const float* __restrict__ in, const float* __restrict__ in2,
    const float* __restrict__ w, float* __restrict__ out, int CIN, int Cout) {
    __shared__ float red[8192];
    conv1x1_tile(in, in2, w, out, CIN, Cout, blockIdx.z, blockIdx.y * 8,
                 blockIdx.x * 64, red);
}

// ----------------------------- host launcher ---------------------------------
extern "C" void kernel_launch(void* const* d_in, const int* in_sizes, int n_in,
                              void* d_out, int out_size, void* d_ws, size_t ws_size,
                              hipStream_t stream) {
    const float* fm      = (const float*)d_in[0];
    const float* last_fm = (const float*)d_in[1];
    const float* lat_w1  = (const float*)d_in[2];
    const float* lat_w3a = (const float*)d_in[3];
    const float* lat_g   = (const float*)d_in[4];
    const float* lat_b   = (const float*)d_in[5];
    const float* lat_m   = (const float*)d_in[6];
    const float* lat_v   = (const float*)d_in[7];
    const float* lat_w3b = (const float*)d_in[8];
    const float* ref_w1  = (const float*)d_in[9];
    const float* ref_w3a = (const float*)d_in[10];
    const float* ref_g   = (const float*)d_in[11];
    const float* ref_b   = (const float*)d_in[12];
    const float* ref_m   = (const float*)d_in[13];
    const float* ref_v   = (const float*)d_in[14];
    const float* ref_w3b = (const float*)d_in[15];
    const float* emb_w   = (const float*)d_in[16];
    float* out = (float*)d_out;

    float* ws      = (float*)d_ws;
    float* lat_x1  = ws;                  // 2*64*1024
    float* lat_t1  = lat_x1 + 131072;
    float* latent  = lat_t1 + 131072;
    float* dist    = latent + 131072;     // 2*1984 (pad 4096)
    float* embed   = dist + 4096;         // 2*32*1024
    float* tfout   = embed + 65536;
    float* ref_x1  = tfout + 131072;
    float* ref_t1  = ref_x1 + 131072;
    int*   pn      = (int*)(ref_t1 + 131072);  // 2*1024
    int*   ordg    = pn + 2048;                // 2*1024
    int*   offg    = ordg + 2048;              // 2*1025 (pad 2080)
    int*   maxd    = offg + 2080;              // 2

    // K0: dist + big conv1x1 fm->lat_x1 + embed conv (all independent)
    k0_fused<<<446, 1024, 0, stream>>>(fm, last_fm, lat_w1, emb_w,
                                       lat_x1, embed, dist);
    // K1: MST (blocks 0,1) || conv3x3a lat_x1->lat_t1
    k1_fused<<<514, 256, 0, stream>>>(dist, pn, maxd, ordg, offg,
                                      lat_x1, lat_w3a, lat_g, lat_b, lat_m, lat_v,
                                      lat_t1);
    // K2: treefilter -> tfout || conv3x3b lat_t1(+lat_x1)->latent
    k2_fused<<<576, 256, 0, stream>>>(last_fm, embed, pn, ordg, offg, maxd,
                                      tfout, lat_t1, lat_w3b, lat_x1, latent);
    // K3: ref conv1x1 on (latent + tfout)
    conv1x1_add_kernel<<<dim3(16, 8, 2), 1024, 0, stream>>>(
        latent, tfout, ref_w1, ref_x1, 64, 64);
    // K4, K5: refine_residual tail
    conv3x3_kernel<<<dim3(4, 64, 2), 256, 0, stream>>>(
        ref_x1, ref_w3a, ref_g, ref_b, ref_m, ref_v, nullptr, ref_t1, 0);
    conv3x3_kernel<<<dim3(4, 64, 2), 256, 0, stream>>>(
        ref_t1, ref_w3b, nullptr, nullptr, nullptr, nullptr, ref_x1, out, 1);
}